// Round 10
// baseline (86.916 us; speedup 1.0000x reference)
//
#include <hip/hip_runtime.h>
#include <hip/hip_bf16.h>

typedef __attribute__((ext_vector_type(8))) short bf16x8;
typedef __attribute__((ext_vector_type(4))) float f32x4;
typedef __attribute__((ext_vector_type(4))) unsigned short u16x4;

#define MFMA16(a, b, c) __builtin_amdgcn_mfma_f32_16x16x32_bf16(a, b, c, 0, 0, 0)

// B=16, S=2048, EMB=512, HEAD_DIM=64
// Q pre-scaled by 0.125 * log2(e): softmax runs in exp2 domain.
#define QSCALE 0.18033688011112042f

#define GLDS16(gp, lp)                                                         \
    __builtin_amdgcn_global_load_lds(                                          \
        (const __attribute__((address_space(1))) void*)(gp),                   \
        (__attribute__((address_space(3))) void*)(lp), 16, 0, 0)

__device__ __forceinline__ short nbf(float f) {
    __hip_bfloat16 h = __float2bfloat16(f);
    return *(short*)&h;
}
__device__ __forceinline__ unsigned short nbfu(float f) {
    __hip_bfloat16 h = __float2bfloat16(f);
    return *(unsigned short*)&h;
}

// Wt[mat][h][e] = bf16(W_mat[e][h])
__global__ void wt_kernel(const float* __restrict__ Wq, const float* __restrict__ Wk,
                          const float* __restrict__ Wv, unsigned short* __restrict__ Wt) {
    const int h = blockIdx.x;
    const int mat = blockIdx.y;
    const int e = threadIdx.x;
    const float* W = (mat == 0) ? Wq : ((mat == 1) ? Wk : Wv);
    Wt[(mat * 64 + h) * 512 + e] = nbfu(W[e * 64 + h]);
}

// Fused QKV projection (unchanged).
__global__ __launch_bounds__(256, 2) void qkv_proj(
    const float* __restrict__ x1, const unsigned short* __restrict__ Wt,
    unsigned short* __restrict__ Q, unsigned short* __restrict__ K,
    unsigned short* __restrict__ Vt)
{
    __shared__ char alds[2][8192];
    __shared__ char blds[2][12288];

    const int tid = threadIdx.x;
    const int w = tid >> 6, lane = tid & 63;
    const int c = lane & 15, g = lane >> 4;
    const int tokB = blockIdx.x * 64;

    const char* x1b = (const char*)x1;
    const char* Wtb = (const char*)Wt;

    const int tA0 = tid >> 3,           qA0 = (tid & 7) ^ (tA0 & 7);
    const int tA1 = (tid + 256) >> 3,   qA1 = (tid & 7) ^ (tA1 & 7);
    const size_t aoff0 = (size_t)(tokB + tA0) * 2048 + qA0 * 16;
    const size_t aoff1 = (size_t)(tokB + tA1) * 2048 + qA1 * 16;

    auto bsrc = [&](int j) -> size_t {
        const int n = j >> 6, c2 = (j >> 2) & 15, g2 = j & 3;
        return (size_t)((n >> 2) * 64 + (n & 3) * 16 + c2) * 1024 + g2 * 16;
    };
    const size_t boff0 = bsrc(tid), boff1 = bsrc(tid + 256), boff2 = bsrc(tid + 512);

    f32x4 acc[12];
#pragma unroll
    for (int n = 0; n < 12; ++n) acc[n] = (f32x4)0.f;

    GLDS16(x1b + aoff0, &alds[0][tid * 16]);
    GLDS16(x1b + aoff1, &alds[0][4096 + tid * 16]);
    GLDS16(Wtb + boff0, &blds[0][tid * 16]);
    GLDS16(Wtb + boff1, &blds[0][4096 + tid * 16]);
    GLDS16(Wtb + boff2, &blds[0][8192 + tid * 16]);

    const int arow = (w * 16 + c) * 128;
    const int aq0 = (((2 * g) ^ (c & 7)) * 16);
    const int aq1 = (((2 * g + 1) ^ (c & 7)) * 16);
    const int brd = (c * 4 + g) * 16;

    int buf = 0;
    for (int ks = 0; ks < 16; ++ks) {
        asm volatile("s_waitcnt vmcnt(0)\n\ts_barrier" ::: "memory");

        if (ks < 15) {
            const size_t ka = (size_t)(ks + 1) * 128;
            const size_t kb = (size_t)(ks + 1) * 64;
            char* ab = &alds[buf ^ 1][0];
            char* bb = &blds[buf ^ 1][0];
            GLDS16(x1b + aoff0 + ka, ab + tid * 16);
            GLDS16(x1b + aoff1 + ka, ab + 4096 + tid * 16);
            GLDS16(Wtb + boff0 + kb, bb + tid * 16);
            GLDS16(Wtb + boff1 + kb, bb + 4096 + tid * 16);
            GLDS16(Wtb + boff2 + kb, bb + 8192 + tid * 16);
        }

        const char* ab = &alds[buf][0];
        const char* bb = &blds[buf][0];
        f32x4 a0 = *(const f32x4*)(ab + arow + aq0);
        f32x4 a1 = *(const f32x4*)(ab + arow + aq1);
        bf16x8 af;
        af[0] = nbf(a0[0]); af[1] = nbf(a0[1]); af[2] = nbf(a0[2]); af[3] = nbf(a0[3]);
        af[4] = nbf(a1[0]); af[5] = nbf(a1[1]); af[6] = nbf(a1[2]); af[7] = nbf(a1[3]);
#pragma unroll
        for (int n = 0; n < 12; ++n) {
            bf16x8 bf = *(const bf16x8*)(bb + n * 1024 + brd);
            acc[n] = MFMA16(af, bf, acc[n]);
        }
        buf ^= 1;
    }

    const int tok0 = tokB + w * 16;
#pragma unroll
    for (int n = 0; n < 4; ++n)
#pragma unroll
        for (int r = 0; r < 4; ++r)
            Q[(size_t)(tok0 + g * 4 + r) * 64 + n * 16 + c] = nbfu(acc[n][r] * QSCALE);
#pragma unroll
    for (int n = 0; n < 4; ++n)
#pragma unroll
        for (int r = 0; r < 4; ++r)
            K[(size_t)(tok0 + g * 4 + r) * 64 + n * 16 + c] = nbfu(acc[4 + n][r]);

    const int b = tok0 >> 11;
    const int sl = (tok0 & 2047) + g * 4;
#pragma unroll
    for (int n = 0; n < 4; ++n) {
        const int d = n * 16 + c;
        u16x4 pv;
#pragma unroll
        for (int r = 0; r < 4; ++r) pv[r] = nbfu(acc[8 + n][r]);
        *(u16x4*)(Vt + ((size_t)(b * 64 + d) << 11) + sl) = pv;
    }
}

// Causal flash attention v8: split-K + K-direct-to-reg + phase-staggered sets.
//  - 8 waves: set 0 (waves 0-3) even 128-key tiles, set 1 (waves 4-7) odd.
//  - K fragments loaded DIRECTLY global->reg (L2-resident): no K in LDS.
//  - V only in LDS, triple-buffered vb3[3][32KB]; set 1 defers its PV by one
//    iteration (P persists in wave-private p_lds, V(j-1) alive in vb3) ->
//    set0 and set1 occupy different pipes at the same instant.
//  - Online-softmax order kept exact: set1 does PV(prev) BEFORE rescale(t).
//  - LDS = 96KB + 32KB P = 128KB -> 1 block/CU, 2 waves/SIMD.
__global__ __launch_bounds__(512, 1) void flash_attn(
    const unsigned short* __restrict__ Q, const unsigned short* __restrict__ K,
    const unsigned short* __restrict__ Vt, float* __restrict__ out)
{
    __shared__ char vb3[3][32768];   // [pair%3][ set0 V 16KB | set1 V 16KB ]
    __shared__ char p_lds[32768];    // [wave 0..7][4KB]

    const int tid = threadIdx.x;
    const int W = tid >> 6;          // 0..7
    const int st = W >> 2;           // key-split set
    const int w = W & 3;             // q-row group
    const int lane = tid & 63;
    const int c = lane & 15, g = lane >> 4;

    const int id = blockIdx.x;
    const int b = 2 * (id & 7) + ((id >> 3) & 1);
    const int qt = 31 - (id >> 4);             // heavy blocks dispatch first
    const int n2 = (qt >> 1) + 1;              // # 128-key tiles
    const int J = (n2 + 1) >> 1;               // super-iterations (tile pairs)
    const int qr0c = qt * 64 + w * 16 + c;
    const size_t qrow_g = ((size_t)b << 11) + qt * 64 + w * 16;

    bf16x8 qf0 = *(const bf16x8*)(Q + (qrow_g + c) * 64 + g * 8);
    bf16x8 qf1 = *(const bf16x8*)(Q + (qrow_g + c) * 64 + 32 + g * 8);

    const char* Kb = (const char*)(K + (((size_t)b << 11) * 64));
    const char* Vb = (const char*)(Vt + (((size_t)b << 11) * 64));   // [d=64][s=2048]

    // V staging decomposition (per-tile 16KB; dst tid*16 = [s4][nn][lane]x16B, h adds 8192)
    const int c2 = tid & 15, g2 = (tid >> 4) & 3, nn = (tid >> 6) & 3, s4 = (tid >> 8) & 1;
    const int voff = (nn * 16 + c2) * 4096 + g2 * 16 + s4 * 64;   // + h*128, + tile*256

    float m = -1e30f, l = 0.f;
    f32x4 acc[4];
#pragma unroll
    for (int n = 0; n < 4; ++n) acc[n] = (f32x4)0.f;

    // ---- helpers ----
    auto STAGE = [&](int p) {   // stage V pair p (tiles 2p, 2p+1) into vb3[p%3]
        char* d = &vb3[p % 3][0];
        const int tA = (2 * p     < n2) ? 2 * p     : n2 - 1;
        const int tB = (2 * p + 1 < n2) ? 2 * p + 1 : n2 - 1;
        const size_t oa = (size_t)tA * 256, ob = (size_t)tB * 256;
        GLDS16(Vb + oa + voff,        d + tid * 16);
        GLDS16(Vb + oa + voff + 128,  d + 8192 + tid * 16);
        GLDS16(Vb + ob + voff,        d + 16384 + tid * 16);
        GLDS16(Vb + ob + voff + 128,  d + 16384 + 8192 + tid * 16);
    };

    auto PV = [&](const char* vbase) {
        const char* pr = &p_lds[W * 4096 + lane * 16];
        bf16x8 pf[4];
#pragma unroll
        for (int ps = 0; ps < 4; ++ps) pf[ps] = *(const bf16x8*)(pr + ps * 1024);
        __builtin_amdgcn_s_setprio(1);
#pragma unroll
        for (int n = 0; n < 4; ++n) {
#pragma unroll
            for (int ps = 0; ps < 4; ++ps) {
                bf16x8 vf = *(const bf16x8*)(vbase + (ps >> 1) * 8192 + (ps & 1) * 4096 + n * 1024 + lane * 16);
                acc[n] = MFMA16(pf[ps], vf, acc[n]);
            }
        }
        __builtin_amdgcn_s_setprio(0);
    };

    STAGE(0);   // prologue

    for (int j = 0; j < J; ++j) {
        asm volatile("s_waitcnt vmcnt(0)\n\ts_barrier" ::: "memory");
        if (j + 1 < J) STAGE(j + 1);

        // set 1: deferred PV of tile 2j-1 (QK'd last iter; V alive in vb3[(j-1)%3])
        if (st == 1 && j >= 1) PV(&vb3[(j - 1) % 3][16384]);

        const int t = 2 * j + st;
        if (t < n2) {
            // ---- K direct global->reg, then QK ----
            const char* kt = Kb + (size_t)t * 16384;
            bf16x8 kf[16];
#pragma unroll
            for (int h = 0; h < 2; ++h)
#pragma unroll
                for (int n = 0; n < 4; ++n) {
                    const char* kp = kt + h * 8192 + (n * 16 + c) * 128 + g * 16;
                    kf[(h * 4 + n) * 2]     = *(const bf16x8*)kp;
                    kf[(h * 4 + n) * 2 + 1] = *(const bf16x8*)(kp + 64);
                }
            f32x4 s[8];
#pragma unroll
            for (int i = 0; i < 8; ++i) s[i] = (f32x4)0.f;
            __builtin_amdgcn_s_setprio(1);
#pragma unroll
            for (int i = 0; i < 8; ++i) {
                s[i] = MFMA16(kf[2 * i], qf0, s[i]);
                s[i] = MFMA16(kf[2 * i + 1], qf1, s[i]);
            }
            __builtin_amdgcn_s_setprio(0);

            // ---- causal mask (this set's diagonal tile only) ----
            if (t == n2 - 1) {
#pragma unroll
                for (int h = 0; h < 2; ++h)
#pragma unroll
                    for (int n = 0; n < 4; ++n) {
                        const int key0 = t * 128 + h * 64 + n * 16 + g * 4;
#pragma unroll
                        for (int r = 0; r < 4; ++r)
                            if (key0 + r > qr0c) s[h * 4 + n][r] = -1e30f;
                    }
            }

            // ---- online softmax (exp2 domain, defer-max THR=8) ----
            float tm = -1e30f;
#pragma unroll
            for (int i = 0; i < 8; ++i)
                tm = fmaxf(tm, fmaxf(fmaxf(s[i][0], s[i][1]), fmaxf(s[i][2], s[i][3])));

            if (__any(tm > m + 8.f)) {
                float gm = tm;
                gm = fmaxf(gm, __shfl_xor(gm, 16, 64));
                gm = fmaxf(gm, __shfl_xor(gm, 32, 64));
                const float mn = fmaxf(m, gm);
                const float alpha = exp2f(m - mn);
                m = mn;
                l *= alpha;
                float al[4];
#pragma unroll
                for (int r = 0; r < 4; ++r) al[r] = __shfl(alpha, g * 4 + r, 16);
#pragma unroll
                for (int n = 0; n < 4; ++n)
#pragma unroll
                    for (int r = 0; r < 4; ++r) acc[n][r] *= al[r];
            }

            char* pw = &p_lds[W * 4096 + ((g >> 1) * 16 + c) * 16 + (g & 1) * 8];
#pragma unroll
            for (int h = 0; h < 2; ++h)
#pragma unroll
                for (int n = 0; n < 4; ++n) {
                    const int i = h * 4 + n;
                    float p0 = exp2f(s[i][0] - m);
                    float p1 = exp2f(s[i][1] - m);
                    float p2 = exp2f(s[i][2] - m);
                    float p3 = exp2f(s[i][3] - m);
                    l += (p0 + p1) + (p2 + p3);
                    u16x4 pk;
                    pk[0] = nbfu(p0); pk[1] = nbfu(p1); pk[2] = nbfu(p2); pk[3] = nbfu(p3);
                    *(u16x4*)(pw + (h * 2 + (n >> 1)) * 1024 + (n & 1) * 512) = pk;
                }

            // set 0: PV of this tile now (V in vb3[j%3], set0 region)
            if (st == 0) PV(&vb3[j % 3][0]);
        }
    }

    // set 1: flush PV of its last QK'd tile (2J-1), if it exists
    if (st == 1 && (2 * J - 1) < n2) PV(&vb3[(J - 1) % 3][16384]);

    // ---- epilogue: merge set 1 into set 0 via LDS ----
    __syncthreads();
    float* accb = (float*)&vb3[0][0];            // [w=4][row=16][col=64] f32
    float* mb = (float*)&vb3[0][16384];          // [w=4][c=16]
    float* lb = (float*)&vb3[0][16384 + 256];    // [w=4][c=16]

    if (st == 1) {
        l += __shfl_xor(l, 16, 64);
        l += __shfl_xor(l, 32, 64);
        if (g == 0) { mb[w * 16 + c] = m; lb[w * 16 + c] = l; }
#pragma unroll
        for (int n = 0; n < 4; ++n)
#pragma unroll
            for (int r = 0; r < 4; ++r)
                accb[w * 1024 + (g * 4 + r) * 64 + n * 16 + c] = acc[n][r];
    }
    __syncthreads();

    if (st == 0) {
        l += __shfl_xor(l, 16, 64);
        l += __shfl_xor(l, 32, 64);
        const float m1c = mb[w * 16 + c];
        const float l1c = lb[w * 16 + c];
        const float mF = fmaxf(m, m1c);
        const float a0 = exp2f(m - mF);                        // set 0 always non-empty
        const float a1 = (m1c > -1e29f) ? exp2f(m1c - mF) : 0.f;
        const float inv = 1.f / (l * a0 + l1c * a1);
        const float s0 = a0 * inv, s1 = a1 * inv;
        float s0r[4], s1r[4];
#pragma unroll
        for (int r = 0; r < 4; ++r) {
            s0r[r] = __shfl(s0, g * 4 + r, 16);
            s1r[r] = __shfl(s1, g * 4 + r, 16);
        }
#pragma unroll
        for (int n = 0; n < 4; ++n)
#pragma unroll
            for (int r = 0; r < 4; ++r) {
                const float a1v = accb[w * 1024 + (g * 4 + r) * 64 + n * 16 + c];
                out[(qrow_g + g * 4 + r) * 64 + n * 16 + c] = acc[n][r] * s0r[r] + a1v * s1r[r];
            }
    }
}

extern "C" void kernel_launch(void* const* d_in, const int* in_sizes, int n_in,
                              void* d_out, int out_size, void* d_ws, size_t ws_size,
                              hipStream_t stream) {
    const float* x1 = (const float*)d_in[0];
    const float* Wq = (const float*)d_in[2];
    const float* Wk = (const float*)d_in[3];
    const float* Wv = (const float*)d_in[4];
    float* out = (float*)d_out;

    unsigned short* Wt  = (unsigned short*)d_ws;
    unsigned short* Qw  = (unsigned short*)((char*)d_ws + 196608);
    unsigned short* Kw  = (unsigned short*)((char*)d_ws + 196608 + 4194304);
    unsigned short* Vtw = (unsigned short*)((char*)d_ws + 196608 + 2 * 4194304);

    wt_kernel<<<dim3(64, 3), 512, 0, stream>>>(Wq, Wk, Wv, Wt);
    qkv_proj<<<512, 256, 0, stream>>>(x1, Wt, Qw, Kw, Vtw);
    flash_attn<<<512, 512, 0, stream>>>(Qw, Kw, Vtw, out);
}

// Round 11
// 65.236 us; speedup vs baseline: 1.3323x; 1.3323x over previous
//
#include <hip/hip_runtime.h>
#include <hip/hip_bf16.h>

typedef __attribute__((ext_vector_type(8))) short bf16x8;
typedef __attribute__((ext_vector_type(4))) float f32x4;
typedef __attribute__((ext_vector_type(4))) unsigned short u16x4;

#define MFMA16(a, b, c) __builtin_amdgcn_mfma_f32_16x16x32_bf16(a, b, c, 0, 0, 0)

// B=16, S=2048, EMB=512, HEAD_DIM=64
// Q pre-scaled by 0.125 * log2(e): softmax runs in exp2 domain.
#define QSCALE 0.18033688011112042f

#define GLDS16(gp, lp)                                                         \
    __builtin_amdgcn_global_load_lds(                                          \
        (const __attribute__((address_space(1))) void*)(gp),                   \
        (__attribute__((address_space(3))) void*)(lp), 16, 0, 0)

__device__ __forceinline__ short nbf(float f) {
    __hip_bfloat16 h = __float2bfloat16(f);
    return *(short*)&h;
}
__device__ __forceinline__ unsigned short nbfu(float f) {
    __hip_bfloat16 h = __float2bfloat16(f);
    return *(unsigned short*)&h;
}

// Wt[mat][h][e] = bf16(W_mat[e][h])
__global__ void wt_kernel(const float* __restrict__ Wq, const float* __restrict__ Wk,
                          const float* __restrict__ Wv, unsigned short* __restrict__ Wt) {
    const int h = blockIdx.x;
    const int mat = blockIdx.y;
    const int e = threadIdx.x;
    const float* W = (mat == 0) ? Wq : ((mat == 1) ? Wk : Wv);
    Wt[(mat * 64 + h) * 512 + e] = nbfu(W[e * 64 + h]);
}

// Fused QKV projection v4: 512-thread / 8-wave blocks (256 blocks = 1/CU,
// 2 waves/SIMD resident — R9 showed big blocks are the occupancy lever that
// works; 2-block co-residency does not materialize). Block covers 128 tokens.
// A tile 128x32e fp32 (16KB, XOR-swizzled slots) + B tile 12KB, both double
// buffered (56KB LDS). Same barrier scheme as before.
__global__ __launch_bounds__(512, 1) void qkv_proj(
    const float* __restrict__ x1, const unsigned short* __restrict__ Wt,
    unsigned short* __restrict__ Q, unsigned short* __restrict__ K,
    unsigned short* __restrict__ Vt)
{
    __shared__ char alds[2][16384];   // A: [128 tok][8 slots]x16B, slot qp holds q=qp^(tok&7)
    __shared__ char blds[2][12288];   // B: [n=12][c2=16][g2=4]x16B fragment order

    const int tid = threadIdx.x;
    const int W = tid >> 6, lane = tid & 63;
    const int c = lane & 15, g = lane >> 4;
    const int tokB = blockIdx.x * 128;

    const char* x1b = (const char*)x1;
    const char* Wtb = (const char*)Wt;

    // A staging: thread stages chunks j = tid, tid+512 (1024 chunks total)
    const int tA0 = tid >> 3,           qA0 = (tid & 7) ^ (tA0 & 7);
    const int tA1 = (tid + 512) >> 3,   qA1 = (tid & 7) ^ (tA1 & 7);
    const size_t aoff0 = (size_t)(tokB + tA0) * 2048 + qA0 * 16;
    const size_t aoff1 = (size_t)(tokB + tA1) * 2048 + qA1 * 16;

    // B staging: chunks j = tid (all), tid+512 (tid<256) -> 768 chunks
    auto bsrc = [&](int j) -> size_t {
        const int n = j >> 6, c2 = (j >> 2) & 15, g2 = j & 3;
        return (size_t)((n >> 2) * 64 + (n & 3) * 16 + c2) * 1024 + g2 * 16;
    };
    const size_t boff0 = bsrc(tid), boff1 = bsrc(tid + 512);

    f32x4 acc[12];
#pragma unroll
    for (int n = 0; n < 12; ++n) acc[n] = (f32x4)0.f;

    // prologue: stage ks=0 into buf 0
    GLDS16(x1b + aoff0, &alds[0][tid * 16]);
    GLDS16(x1b + aoff1, &alds[0][8192 + tid * 16]);
    GLDS16(Wtb + boff0, &blds[0][tid * 16]);
    if (tid < 256) GLDS16(Wtb + boff1, &blds[0][8192 + tid * 16]);

    const int arow = (W * 16 + c) * 128;
    const int aq0 = (((2 * g) ^ (c & 7)) * 16);
    const int aq1 = (((2 * g + 1) ^ (c & 7)) * 16);
    const int brd = (c * 4 + g) * 16;

    int buf = 0;
    for (int ks = 0; ks < 16; ++ks) {
        asm volatile("s_waitcnt vmcnt(0)\n\ts_barrier" ::: "memory");

        if (ks < 15) {
            const size_t ka = (size_t)(ks + 1) * 128;
            const size_t kb = (size_t)(ks + 1) * 64;
            char* ab = &alds[buf ^ 1][0];
            char* bb = &blds[buf ^ 1][0];
            GLDS16(x1b + aoff0 + ka, ab + tid * 16);
            GLDS16(x1b + aoff1 + ka, ab + 8192 + tid * 16);
            GLDS16(Wtb + boff0 + kb, bb + tid * 16);
            if (tid < 256) GLDS16(Wtb + boff1 + kb, bb + 8192 + tid * 16);
        }

        const char* ab = &alds[buf][0];
        const char* bb = &blds[buf][0];
        f32x4 a0 = *(const f32x4*)(ab + arow + aq0);
        f32x4 a1 = *(const f32x4*)(ab + arow + aq1);
        bf16x8 af;
        af[0] = nbf(a0[0]); af[1] = nbf(a0[1]); af[2] = nbf(a0[2]); af[3] = nbf(a0[3]);
        af[4] = nbf(a1[0]); af[5] = nbf(a1[1]); af[6] = nbf(a1[2]); af[7] = nbf(a1[3]);
#pragma unroll
        for (int n = 0; n < 12; ++n) {
            bf16x8 bf = *(const bf16x8*)(bb + n * 1024 + brd);
            acc[n] = MFMA16(af, bf, acc[n]);
        }
        buf ^= 1;
    }

    const int tok0 = tokB + W * 16;
#pragma unroll
    for (int n = 0; n < 4; ++n)
#pragma unroll
        for (int r = 0; r < 4; ++r)
            Q[(size_t)(tok0 + g * 4 + r) * 64 + n * 16 + c] = nbfu(acc[n][r] * QSCALE);
#pragma unroll
    for (int n = 0; n < 4; ++n)
#pragma unroll
        for (int r = 0; r < 4; ++r)
            K[(size_t)(tok0 + g * 4 + r) * 64 + n * 16 + c] = nbfu(acc[4 + n][r]);

    const int b = tok0 >> 11;
    const int sl = (tok0 & 2047) + g * 4;
#pragma unroll
    for (int n = 0; n < 4; ++n) {
        const int d = n * 16 + c;
        u16x4 pv;
#pragma unroll
        for (int r = 0; r < 4; ++r) pv[r] = nbfu(acc[8 + n][r]);
        *(u16x4*)(Vt + ((size_t)(b * 64 + d) << 11) + sl) = pv;
    }
}

// Causal flash attention v7 (R9 verbatim — 40.6us known-good): in-block split-K.
__global__ __launch_bounds__(512, 1) void flash_attn(
    const unsigned short* __restrict__ Q, const unsigned short* __restrict__ K,
    const unsigned short* __restrict__ Vt, float* __restrict__ out)
{
    __shared__ char kv[2][65536];   // [buf][ tileA K 16K | tileA V 16K | tileB K 16K | tileB V 16K ]
    __shared__ char p_lds[32768];   // [wave 0..7][ps=4][lane=64]x16B

    const int tid = threadIdx.x;
    const int W = tid >> 6;         // 0..7
    const int st = W >> 2;          // key-split set
    const int w = W & 3;            // q-row group
    const int lane = tid & 63;
    const int c = lane & 15, g = lane >> 4;

    const int id = blockIdx.x;
    const int b = 2 * (id & 7) + ((id >> 3) & 1);
    const int qt = 31 - (id >> 4);            // heavy blocks dispatch first
    const int n2 = (qt >> 1) + 1;             // # 128-key tiles
    const int J = (n2 + 1) >> 1;              // super-iterations (tile pairs)
    const int qr0c = qt * 64 + w * 16 + c;
    const size_t qrow_g = ((size_t)b << 11) + qt * 64 + w * 16;

    bf16x8 qf0 = *(const bf16x8*)(Q + (qrow_g + c) * 64 + g * 8);
    bf16x8 qf1 = *(const bf16x8*)(Q + (qrow_g + c) * 64 + 32 + g * 8);

    const char* Kb = (const char*)(K + (((size_t)b << 11) * 64));
    const char* Vb = (const char*)(Vt + (((size_t)b << 11) * 64));   // [d=64][s=2048]

    const int c2 = tid & 15, g2 = (tid >> 4) & 3, nn = (tid >> 6) & 3, s4 = (tid >> 8) & 1;
    const int koff = (nn * 16 + c2) * 128 + g2 * 16 + s4 * 64;    // +8192 for h=1
    const int voff = (nn * 16 + c2) * 4096 + g2 * 16 + s4 * 64;   // +128  for h=1

    float m = -1e30f, l = 0.f;
    f32x4 acc[4];
#pragma unroll
    for (int n = 0; n < 4; ++n) acc[n] = (f32x4)0.f;

    {   // prologue: stage pair 0 into buf 0 (8 GLDS/thread)
        char* d = &kv[0][0];
        GLDS16(Kb + koff,                 d + tid * 16);
        GLDS16(Kb + koff + 8192,          d + 8192 + tid * 16);
        GLDS16(Vb + voff,                 d + 16384 + tid * 16);
        GLDS16(Vb + voff + 128,           d + 16384 + 8192 + tid * 16);
        GLDS16(Kb + 16384 + koff,         d + 32768 + tid * 16);
        GLDS16(Kb + 16384 + koff + 8192,  d + 32768 + 8192 + tid * 16);
        GLDS16(Vb + 256 + voff,           d + 49152 + tid * 16);
        GLDS16(Vb + 256 + voff + 128,     d + 49152 + 8192 + tid * 16);
    }

    for (int j = 0; j < J; ++j) {
        asm volatile("s_waitcnt vmcnt(0)\n\ts_barrier" ::: "memory");

        if (j + 1 < J) {
            const size_t kA = (size_t)(2 * j + 2) * 16384;
            const size_t vA = (size_t)(2 * j + 2) * 256;
            char* d = &kv[(j & 1) ^ 1][0];
            GLDS16(Kb + kA + koff,                 d + tid * 16);
            GLDS16(Kb + kA + koff + 8192,          d + 8192 + tid * 16);
            GLDS16(Vb + vA + voff,                 d + 16384 + tid * 16);
            GLDS16(Vb + vA + voff + 128,           d + 16384 + 8192 + tid * 16);
            GLDS16(Kb + kA + 16384 + koff,         d + 32768 + tid * 16);
            GLDS16(Kb + kA + 16384 + koff + 8192,  d + 32768 + 8192 + tid * 16);
            GLDS16(Vb + vA + 256 + voff,           d + 49152 + tid * 16);
            GLDS16(Vb + vA + 256 + voff + 128,     d + 49152 + 8192 + tid * 16);
        }

        const int t = 2 * j + st;
        if (t < n2) {
            const char* kb = &kv[j & 1][st * 32768];
            const char* vb = kb + 16384;

            f32x4 s[8];
#pragma unroll
            for (int i = 0; i < 8; ++i) s[i] = (f32x4)0.f;
            __builtin_amdgcn_s_setprio(1);
#pragma unroll
            for (int h = 0; h < 2; ++h)
#pragma unroll
                for (int n = 0; n < 4; ++n) {
                    bf16x8 ka0 = *(const bf16x8*)(kb + h * 8192 + n * 1024 + lane * 16);
                    bf16x8 ka1 = *(const bf16x8*)(kb + h * 8192 + 4096 + n * 1024 + lane * 16);
                    s[h * 4 + n] = MFMA16(ka0, qf0, s[h * 4 + n]);
                    s[h * 4 + n] = MFMA16(ka1, qf1, s[h * 4 + n]);
                }
            __builtin_amdgcn_s_setprio(0);

            if (t == n2 - 1) {
#pragma unroll
                for (int h = 0; h < 2; ++h)
#pragma unroll
                    for (int n = 0; n < 4; ++n) {
                        const int key0 = t * 128 + h * 64 + n * 16 + g * 4;
#pragma unroll
                        for (int r = 0; r < 4; ++r)
                            if (key0 + r > qr0c) s[h * 4 + n][r] = -1e30f;
                    }
            }

            float tm = -1e30f;
#pragma unroll
            for (int i = 0; i < 8; ++i)
                tm = fmaxf(tm, fmaxf(fmaxf(s[i][0], s[i][1]), fmaxf(s[i][2], s[i][3])));

            if (__any(tm > m + 8.f)) {
                float gm = tm;
                gm = fmaxf(gm, __shfl_xor(gm, 16, 64));
                gm = fmaxf(gm, __shfl_xor(gm, 32, 64));
                const float mn = fmaxf(m, gm);
                const float alpha = exp2f(m - mn);
                m = mn;
                l *= alpha;
                float al[4];
#pragma unroll
                for (int r = 0; r < 4; ++r) al[r] = __shfl(alpha, g * 4 + r, 16);
#pragma unroll
                for (int n = 0; n < 4; ++n)
#pragma unroll
                    for (int r = 0; r < 4; ++r) acc[n][r] *= al[r];
            }

            char* pw = &p_lds[W * 4096 + ((g >> 1) * 16 + c) * 16 + (g & 1) * 8];
#pragma unroll
            for (int h = 0; h < 2; ++h)
#pragma unroll
                for (int n = 0; n < 4; ++n) {
                    const int i = h * 4 + n;
                    float p0 = exp2f(s[i][0] - m);
                    float p1 = exp2f(s[i][1] - m);
                    float p2 = exp2f(s[i][2] - m);
                    float p3 = exp2f(s[i][3] - m);
                    l += (p0 + p1) + (p2 + p3);
                    u16x4 pk;
                    pk[0] = nbfu(p0); pk[1] = nbfu(p1); pk[2] = nbfu(p2); pk[3] = nbfu(p3);
                    *(u16x4*)(pw + (h * 2 + (n >> 1)) * 1024 + (n & 1) * 512) = pk;
                }

            const char* pr = &p_lds[W * 4096 + lane * 16];
            bf16x8 pf[4];
#pragma unroll
            for (int ps = 0; ps < 4; ++ps) pf[ps] = *(const bf16x8*)(pr + ps * 1024);
            __builtin_amdgcn_s_setprio(1);
#pragma unroll
            for (int n = 0; n < 4; ++n) {
#pragma unroll
                for (int ps = 0; ps < 4; ++ps) {
                    bf16x8 vf = *(const bf16x8*)(vb + (ps >> 1) * 8192 + (ps & 1) * 4096 + n * 1024 + lane * 16);
                    acc[n] = MFMA16(pf[ps], vf, acc[n]);
                }
            }
            __builtin_amdgcn_s_setprio(0);
        }
    }

    // ---- epilogue: merge set 1 into set 0 via LDS ----
    __syncthreads();
    float* accb = (float*)&kv[0][0];            // [w=4][row=16][col=64] f32
    float* mb = (float*)&kv[0][16384];          // [w=4][c=16]
    float* lb = (float*)&kv[0][16384 + 256];    // [w=4][c=16]

    if (st == 1) {
        l += __shfl_xor(l, 16, 64);
        l += __shfl_xor(l, 32, 64);
        if (g == 0) { mb[w * 16 + c] = m; lb[w * 16 + c] = l; }
#pragma unroll
        for (int n = 0; n < 4; ++n)
#pragma unroll
            for (int r = 0; r < 4; ++r)
                accb[w * 1024 + (g * 4 + r) * 64 + n * 16 + c] = acc[n][r];
    }
    __syncthreads();

    if (st == 0) {
        l += __shfl_xor(l, 16, 64);
        l += __shfl_xor(l, 32, 64);
        const float m1c = mb[w * 16 + c];
        const float l1c = lb[w * 16 + c];
        const float mF = fmaxf(m, m1c);
        const float a0 = exp2f(m - mF);                        // set 0 always non-empty
        const float a1 = (m1c > -1e29f) ? exp2f(m1c - mF) : 0.f;
        const float inv = 1.f / (l * a0 + l1c * a1);
        const float s0 = a0 * inv, s1 = a1 * inv;
        float s0r[4], s1r[4];
#pragma unroll
        for (int r = 0; r < 4; ++r) {
            s0r[r] = __shfl(s0, g * 4 + r, 16);
            s1r[r] = __shfl(s1, g * 4 + r, 16);
        }
#pragma unroll
        for (int n = 0; n < 4; ++n)
#pragma unroll
            for (int r = 0; r < 4; ++r) {
                const float a1v = accb[w * 1024 + (g * 4 + r) * 64 + n * 16 + c];
                out[(qrow_g + g * 4 + r) * 64 + n * 16 + c] = acc[n][r] * s0r[r] + a1v * s1r[r];
            }
    }
}

extern "C" void kernel_launch(void* const* d_in, const int* in_sizes, int n_in,
                              void* d_out, int out_size, void* d_ws, size_t ws_size,
                              hipStream_t stream) {
    const float* x1 = (const float*)d_in[0];
    const float* Wq = (const float*)d_in[2];
    const float* Wk = (const float*)d_in[3];
    const float* Wv = (const float*)d_in[4];
    float* out = (float*)d_out;

    unsigned short* Wt  = (unsigned short*)d_ws;
    unsigned short* Qw  = (unsigned short*)((char*)d_ws + 196608);
    unsigned short* Kw  = (unsigned short*)((char*)d_ws + 196608 + 4194304);
    unsigned short* Vtw = (unsigned short*)((char*)d_ws + 196608 + 2 * 4194304);

    wt_kernel<<<dim3(64, 3), 512, 0, stream>>>(Wq, Wk, Wv, Wt);
    qkv_proj<<<256, 512, 0, stream>>>(x1, Wt, Qw, Kw, Vtw);
    flash_attn<<<512, 512, 0, stream>>>(Qw, Kw, Vtw, out);
}